// Round 3
// baseline (395.552 us; speedup 1.0000x reference)
//
#include <hip/hip_runtime.h>
#include <hip/hip_fp16.h>

#define TOPK 32
#define EMB 64
#define NSLICE 8          // 8 slices x 16B fp16 = 128B row; 3.2MB/slice < 4MiB L2/XCD

// =====================================================================
// Kernel 1 (fused prep): three independent roles split by block range.
//  role A: emb fp32 [N,64] -> embT fp16 slice-major: region s = (N+1) rows x 8 halfs
//  role B: wei/nei -> neiT[k][n] (masked idx -> N = zero row), scale[n] = 1/cnt
//  role Z: zero row (row index N) of each region
// =====================================================================
__global__ __launch_bounds__(256) void prep_kernel(
    const float* __restrict__ emb,
    const float* __restrict__ wei,
    const int*   __restrict__ nei,
    __half* __restrict__ embT,
    int*    __restrict__ neiT,
    float*  __restrict__ scale,
    int n_nodes, int a_blocks, int b_blocks)
{
    const int t = threadIdx.x;
    const size_t regionHalfs = (size_t)(n_nodes + 1) * 8;

    if ((int)blockIdx.x < a_blocks) {
        // ---- role A: 64 nodes per block, LDS transpose, coalesced in & out ----
        const int base = blockIdx.x * 64;
        __shared__ __half lds[64 * 72];              // row stride 72 halfs = 144B (16B-mult)
        const float4* src = (const float4*)emb + (size_t)base * 16;
        #pragma unroll
        for (int i = 0; i < 4; ++i) {
            const int f = t + 256 * i;               // float4 index within 64-row tile
            const int nl = f >> 4, part = f & 15;
            if (base + nl < n_nodes) {
                float4 v = src[f];
                __half2 h0 = __floats2half2_rn(v.x, v.y);
                __half2 h1 = __floats2half2_rn(v.z, v.w);
                *(__half2*)(&lds[nl * 72 + part * 4])     = h0;
                *(__half2*)(&lds[nl * 72 + part * 4 + 2]) = h1;
            }
        }
        __syncthreads();
        #pragma unroll
        for (int i = 0; i < 2; ++i) {
            const int w = t + 256 * i;               // (slice, node_local)
            const int s = w >> 6, nl = w & 63;
            if (base + nl < n_nodes) {
                float4 v = *(const float4*)(&lds[nl * 72 + s * 8]);
                *(float4*)(embT + (size_t)s * regionHalfs + (size_t)(base + nl) * 8) = v;
            }
        }
    } else if ((int)blockIdx.x < a_blocks + b_blocks) {
        // ---- role B: one thread per node ----
        const int n = ((int)blockIdx.x - a_blocks) * 256 + t;
        if (n < n_nodes) {
            const int4*   nrow = (const int4*)(nei + (size_t)n * TOPK);
            const float4* wrow = (const float4*)(wei + (size_t)n * TOPK);
            float cnt = 0.0f;
            #pragma unroll
            for (int q = 0; q < 8; ++q) {
                int4   j4 = nrow[q];
                float4 w4 = wrow[q];
                int o0 = (w4.x != 0.0f) ? j4.x : n_nodes; cnt += (w4.x != 0.0f) ? 1.0f : 0.0f;
                int o1 = (w4.y != 0.0f) ? j4.y : n_nodes; cnt += (w4.y != 0.0f) ? 1.0f : 0.0f;
                int o2 = (w4.z != 0.0f) ? j4.z : n_nodes; cnt += (w4.z != 0.0f) ? 1.0f : 0.0f;
                int o3 = (w4.w != 0.0f) ? j4.w : n_nodes; cnt += (w4.w != 0.0f) ? 1.0f : 0.0f;
                neiT[(size_t)(q * 4 + 0) * n_nodes + n] = o0;
                neiT[(size_t)(q * 4 + 1) * n_nodes + n] = o1;
                neiT[(size_t)(q * 4 + 2) * n_nodes + n] = o2;
                neiT[(size_t)(q * 4 + 3) * n_nodes + n] = o3;
            }
            scale[n] = 1.0f / (cnt + 1e-12f);
        }
    } else {
        // ---- role Z: zero row at index n_nodes of each region ----
        if (t < NSLICE) {
            float4 z = make_float4(0.f, 0.f, 0.f, 0.f);
            *(float4*)(embT + (size_t)t * regionHalfs + (size_t)n_nodes * 8) = z;
        }
    }
}

// =====================================================================
// Kernel 2: sliced gather. slice = blockIdx % 8 -> pinned to one XCD by
// round-robin dispatch; that XCD's L2 caches its whole 3.2MB slice.
// One thread per (node, slice): 32 x 16B L2-hit gathers, no mask logic.
// =====================================================================
__global__ __launch_bounds__(256) void gather_sliced_kernel(
    const __half* __restrict__ embT,
    const int*    __restrict__ neiT,
    const float*  __restrict__ scale,
    float*        __restrict__ out,
    int n_nodes)
{
    const int s = blockIdx.x & 7;
    const int n = ((int)blockIdx.x >> 3) * 256 + threadIdx.x;
    if (n >= n_nodes) return;

    const __half* region = embT + (size_t)s * (size_t)(n_nodes + 1) * 8;

    float acc[8] = {0.f, 0.f, 0.f, 0.f, 0.f, 0.f, 0.f, 0.f};
    #pragma unroll
    for (int b = 0; b < 4; ++b) {
        int idx[8];
        #pragma unroll
        for (int k = 0; k < 8; ++k)
            idx[k] = neiT[(size_t)(b * 8 + k) * n_nodes + n];   // coalesced stream
        float4 r[8];
        #pragma unroll
        for (int k = 0; k < 8; ++k)
            r[k] = *(const float4*)(region + (size_t)idx[k] * 8);  // 16B L2-hit gather
        #pragma unroll
        for (int k = 0; k < 8; ++k) {
            const __half2* hp = (const __half2*)&r[k];
            #pragma unroll
            for (int q = 0; q < 4; ++q) {
                float2 f = __half22float2(hp[q]);
                acc[q * 2]     += f.x;
                acc[q * 2 + 1] += f.y;
            }
        }
    }

    const float sc = scale[n];
    float4 o0, o1;
    o0.x = acc[0] * sc; o0.y = acc[1] * sc; o0.z = acc[2] * sc; o0.w = acc[3] * sc;
    o1.x = acc[4] * sc; o1.y = acc[5] * sc; o1.z = acc[6] * sc; o1.w = acc[7] * sc;
    float* op = out + (size_t)n * EMB + s * 8;
    *(float4*)op       = o0;
    *(float4*)(op + 4) = o1;
}

// =====================================================================
// Fallback 1 (ws >= 25.6MB): verified R2 fp16 path
// =====================================================================
__global__ __launch_bounds__(256) void cvt_f32_to_f16(
    const float* __restrict__ src, __half* __restrict__ dst, int total4)
{
    int i = blockIdx.x * blockDim.x + threadIdx.x;
    if (i < total4) {
        float4 v = ((const float4*)src)[i];
        ((__half2*)dst)[i * 2]     = __floats2half2_rn(v.x, v.y);
        ((__half2*)dst)[i * 2 + 1] = __floats2half2_rn(v.z, v.w);
    }
}

__global__ __launch_bounds__(256) void pprgo_h_kernel(
    const __half* __restrict__ emb,
    const float*  __restrict__ wei,
    const int*    __restrict__ nei,
    float*        __restrict__ out,
    int n_nodes)
{
    const int tid  = blockIdx.x * blockDim.x + threadIdx.x;
    const int n    = tid >> 3;
    const int lane = tid & 7;
    if (n >= n_nodes) return;
    const long base = (long)n * TOPK;
    float w[4]; int idx[4];
    #pragma unroll
    for (int t = 0; t < 4; ++t) {
        w[t]   = wei[base + t * 8 + lane];
        idx[t] = nei[base + t * 8 + lane];
    }
    float m[4];
    #pragma unroll
    for (int t = 0; t < 4; ++t) m[t] = (w[t] != 0.0f) ? 1.0f : 0.0f;
    float acc[8] = {0.f,0.f,0.f,0.f,0.f,0.f,0.f,0.f};
    float cnt = 0.0f;
    #pragma unroll
    for (int t = 0; t < 4; ++t) {
        int j[8]; float a[8];
        #pragma unroll
        for (int k = 0; k < 8; ++k) { j[k] = __shfl(idx[t], k, 8); a[k] = __shfl(m[t], k, 8); }
        float4 r[8];
        #pragma unroll
        for (int k = 0; k < 8; ++k) r[k] = *(const float4*)(emb + (size_t)j[k] * EMB + lane * 8);
        #pragma unroll
        for (int k = 0; k < 8; ++k) {
            const __half2* hp = (const __half2*)&r[k];
            #pragma unroll
            for (int q = 0; q < 4; ++q) {
                float2 f = __half22float2(hp[q]);
                acc[q*2] += a[k]*f.x; acc[q*2+1] += a[k]*f.y;
            }
            cnt += a[k];
        }
    }
    const float sc = 1.0f / (cnt + 1e-12f);
    float4 o0, o1;
    o0.x=acc[0]*sc; o0.y=acc[1]*sc; o0.z=acc[2]*sc; o0.w=acc[3]*sc;
    o1.x=acc[4]*sc; o1.y=acc[5]*sc; o1.z=acc[6]*sc; o1.w=acc[7]*sc;
    float* op = out + (size_t)n * EMB + lane * 8;
    *(float4*)op = o0; *(float4*)(op+4) = o1;
}

// =====================================================================
// Fallback 2 (tiny ws): verified R0 fp32 kernel
// =====================================================================
__global__ __launch_bounds__(256) void pprgo_f32_kernel(
    const float* __restrict__ emb,
    const float* __restrict__ wei,
    const int*   __restrict__ nei,
    float*       __restrict__ out,
    int n_nodes)
{
    const int tid   = blockIdx.x * blockDim.x + threadIdx.x;
    const int group = tid >> 4;
    const int lane  = tid & 15;
    if (group >= n_nodes) return;
    const long base = (long)group * TOPK;
    const float w0 = wei[base + lane];
    const float w1 = wei[base + 16 + lane];
    const int   i0 = nei[base + lane];
    const int   i1 = nei[base + 16 + lane];
    const float m0 = (w0 != 0.0f) ? 1.0f : 0.0f;
    const float m1 = (w1 != 0.0f) ? 1.0f : 0.0f;
    float4 acc = make_float4(0.f,0.f,0.f,0.f);
    float  cnt = 0.0f;
    #pragma unroll 8
    for (int k = 0; k < 16; ++k) {
        const int   j0 = __shfl(i0, k, 16);
        const float a0 = __shfl(m0, k, 16);
        const float4 r0 = *(const float4*)(emb + (size_t)j0 * EMB + lane * 4);
        acc.x += a0*r0.x; acc.y += a0*r0.y; acc.z += a0*r0.z; acc.w += a0*r0.w; cnt += a0;
        const int   j1 = __shfl(i1, k, 16);
        const float a1 = __shfl(m1, k, 16);
        const float4 r1 = *(const float4*)(emb + (size_t)j1 * EMB + lane * 4);
        acc.x += a1*r1.x; acc.y += a1*r1.y; acc.z += a1*r1.z; acc.w += a1*r1.w; cnt += a1;
    }
    const float sc = 1.0f / (cnt + 1e-12f);
    float4 o;
    o.x=acc.x*sc; o.y=acc.y*sc; o.z=acc.z*sc; o.w=acc.w*sc;
    *(float4*)(out + (size_t)group * EMB + lane * 4) = o;
}

extern "C" void kernel_launch(void* const* d_in, const int* in_sizes, int n_in,
                              void* d_out, int out_size, void* d_ws, size_t ws_size,
                              hipStream_t stream) {
    const float* emb = (const float*)d_in[0];   // [N, 64] fp32
    const float* wei = (const float*)d_in[1];   // [N, 32] fp32
    const int*   nei = (const int*)d_in[2];     // [N, 32] int32
    float*       out = (float*)d_out;           // [N, 1, 64] fp32

    const int n_nodes = in_sizes[1] / TOPK;     // 200000

    // workspace layout for the sliced path
    const size_t embT_bytes  = (size_t)NSLICE * (size_t)(n_nodes + 1) * 8 * sizeof(__half); // 25.6MB
    const size_t neiT_bytes  = (size_t)TOPK * n_nodes * sizeof(int);                        // 25.6MB
    const size_t scale_bytes = (size_t)n_nodes * sizeof(float);                             // 0.8MB
    const size_t need_sliced = embT_bytes + neiT_bytes + scale_bytes;                       // ~52MB
    const size_t need_h      = (size_t)n_nodes * EMB * sizeof(__half);                      // 25.6MB

    if (ws_size >= need_sliced) {
        __half* embT  = (__half*)d_ws;
        int*    neiT  = (int*)((char*)d_ws + embT_bytes);
        float*  scale = (float*)((char*)d_ws + embT_bytes + neiT_bytes);

        const int a_blocks = (n_nodes + 63) / 64;        // 3125
        const int b_blocks = (n_nodes + 255) / 256;      // 782
        const int prep_blocks = a_blocks + b_blocks + 1; // +1 zero-row block
        prep_kernel<<<prep_blocks, 256, 0, stream>>>(
            emb, wei, nei, embT, neiT, scale, n_nodes, a_blocks, b_blocks);

        const int gather_blocks = NSLICE * ((n_nodes + 255) / 256);  // 6256
        gather_sliced_kernel<<<gather_blocks, 256, 0, stream>>>(
            embT, neiT, scale, out, n_nodes);
    } else if (ws_size >= need_h) {
        __half* embh = (__half*)d_ws;
        const int total4 = n_nodes * EMB / 4;
        cvt_f32_to_f16<<<(total4 + 255) / 256, 256, 0, stream>>>(emb, embh, total4);
        const int threads = n_nodes * 8;
        pprgo_h_kernel<<<(threads + 255) / 256, 256, 0, stream>>>(embh, wei, nei, out, n_nodes);
    } else {
        const int threads = n_nodes * 16;
        pprgo_f32_kernel<<<(threads + 255) / 256, 256, 0, stream>>>(emb, wei, nei, out, n_nodes);
    }
}

// Round 5
// 221.334 us; speedup vs baseline: 1.7871x; 1.7871x over previous
//
#include <hip/hip_runtime.h>

#define TOPK 32
#define EMB 64

// =====================================================================
// k0: block-partial |max| over emb. 1024 partials, no atomics (deterministic).
// =====================================================================
__global__ __launch_bounds__(256) void absmax_partial_kernel(
    const float* __restrict__ emb, float* __restrict__ partial, int total4)
{
    const float4* src = (const float4*)emb;
    float m = 0.0f;
    for (int i = blockIdx.x * 256 + threadIdx.x; i < total4; i += gridDim.x * 256) {
        float4 v = src[i];
        m = fmaxf(m, fmaxf(fmaxf(fabsf(v.x), fabsf(v.y)),
                           fmaxf(fabsf(v.z), fabsf(v.w))));
    }
    __shared__ float red[256];
    red[threadIdx.x] = m;
    __syncthreads();
    for (int s = 128; s > 0; s >>= 1) {
        if (threadIdx.x < s) red[threadIdx.x] = fmaxf(red[threadIdx.x], red[threadIdx.x + s]);
        __syncthreads();
    }
    if (threadIdx.x == 0) partial[blockIdx.x] = red[0];
}

// =====================================================================
// k1: every block redundantly reduces the 1024 partials -> global max.
//  blocks [0, a_blocks): quantize emb fp32 -> int8 (16 elems/thread)
//  block  a_blocks:      zero row at index N (exactly 64B!) + store step
// =====================================================================
__global__ __launch_bounds__(256) void quant_kernel(
    const float* __restrict__ emb, signed char* __restrict__ emb8,
    const float* __restrict__ partial, float* __restrict__ stepOut,
    int n_nodes, int a_blocks)
{
    const int t = threadIdx.x;
    __shared__ float red[256];
    float m = fmaxf(fmaxf(partial[t], partial[t + 256]),
                    fmaxf(partial[t + 512], partial[t + 768]));
    red[t] = m;
    __syncthreads();
    for (int s = 128; s > 0; s >>= 1) {
        if (t < s) red[t] = fmaxf(red[t], red[t + s]);
        __syncthreads();
    }
    const float maxv = fmaxf(red[0], 1e-20f);
    const float inv_step = 127.0f / maxv;

    if ((int)blockIdx.x < a_blocks) {
        const int gid = blockIdx.x * 256 + t;              // 16 elems per thread
        const int total16 = n_nodes * (EMB / 16);
        if (gid < total16) {
            const float4* src = (const float4*)emb + (size_t)gid * 4;
            unsigned int w[4];
            #pragma unroll
            for (int p = 0; p < 4; ++p) {
                float4 v = src[p];
                int q0 = (int)__builtin_rintf(fminf(fmaxf(v.x * inv_step, -127.f), 127.f));
                int q1 = (int)__builtin_rintf(fminf(fmaxf(v.y * inv_step, -127.f), 127.f));
                int q2 = (int)__builtin_rintf(fminf(fmaxf(v.z * inv_step, -127.f), 127.f));
                int q3 = (int)__builtin_rintf(fminf(fmaxf(v.w * inv_step, -127.f), 127.f));
                w[p] = (unsigned int)(q0 & 0xff) | ((unsigned int)(q1 & 0xff) << 8) |
                       ((unsigned int)(q2 & 0xff) << 16) | ((unsigned int)(q3 & 0xff) << 24);
            }
            ((int4*)emb8)[gid] = make_int4((int)w[0], (int)w[1], (int)w[2], (int)w[3]);
        }
    } else {
        // zero row = 64 bytes = exactly 4 int4  (R4's bug was overrunning this)
        if (t < 4)
            ((int4*)(emb8 + (size_t)n_nodes * EMB))[t] = make_int4(0, 0, 0, 0);
        if (t == 0) stepOut[0] = maxv / 127.0f;
    }
}

// =====================================================================
// k2: gather. R2's proven shape: 8 lanes/node, inline mask (masked -> row N
// of zeros), 32 x 64B row gathers (uint2/lane), exact int32 accumulate.
// =====================================================================
__global__ __launch_bounds__(256) void gather_q8_kernel(
    const signed char* __restrict__ emb8,
    const float* __restrict__ wei,
    const int*   __restrict__ nei,
    const float* __restrict__ stepPtr,
    float*       __restrict__ out,
    int n_nodes)
{
    const int tid  = blockIdx.x * 256 + threadIdx.x;
    const int n    = tid >> 3;
    const int lane = tid & 7;
    if (n >= n_nodes) return;

    const float step = stepPtr[0];
    const long base = (long)n * TOPK;
    const int4   j4 = *(const int4*)(nei + base + lane * 4);
    const float4 w4 = *(const float4*)(wei + base + lane * 4);
    int jm[4];
    jm[0] = (w4.x != 0.0f) ? j4.x : n_nodes;
    jm[1] = (w4.y != 0.0f) ? j4.y : n_nodes;
    jm[2] = (w4.z != 0.0f) ? j4.z : n_nodes;
    jm[3] = (w4.w != 0.0f) ? j4.w : n_nodes;

    int acc[8] = {0, 0, 0, 0, 0, 0, 0, 0};
    int cnt = 0;

    #pragma unroll
    for (int t2 = 0; t2 < 4; ++t2) {
        // row r = t2*8 + k lives in lane 2*t2 + (k>>2), component k&3
        int j[8];
        #pragma unroll
        for (int k = 0; k < 8; ++k)
            j[k] = __shfl(jm[k & 3], t2 * 2 + (k >> 2), 8);
        uint2 r[8];
        #pragma unroll
        for (int k = 0; k < 8; ++k)
            r[k] = *(const uint2*)(emb8 + (size_t)j[k] * EMB + lane * 8);
        #pragma unroll
        for (int k = 0; k < 8; ++k) {
            cnt += (j[k] != n_nodes) ? 1 : 0;
            const unsigned int x = r[k].x, y = r[k].y;
            acc[0] += (int)(signed char)(x & 0xff);
            acc[1] += (int)(signed char)((x >> 8) & 0xff);
            acc[2] += (int)(signed char)((x >> 16) & 0xff);
            acc[3] += ((int)x) >> 24;
            acc[4] += (int)(signed char)(y & 0xff);
            acc[5] += (int)(signed char)((y >> 8) & 0xff);
            acc[6] += (int)(signed char)((y >> 16) & 0xff);
            acc[7] += ((int)y) >> 24;
        }
    }

    const float mlt = step / ((float)cnt + 1e-12f);
    float4 o0, o1;
    o0.x = acc[0] * mlt; o0.y = acc[1] * mlt; o0.z = acc[2] * mlt; o0.w = acc[3] * mlt;
    o1.x = acc[4] * mlt; o1.y = acc[5] * mlt; o1.z = acc[6] * mlt; o1.w = acc[7] * mlt;
    float* op = out + (size_t)n * EMB + lane * 8;
    *(float4*)op       = o0;
    *(float4*)(op + 4) = o1;
}

// =====================================================================
// Fallback (tiny ws): verified R0 fp32 kernel
// =====================================================================
__global__ __launch_bounds__(256) void pprgo_f32_kernel(
    const float* __restrict__ emb,
    const float* __restrict__ wei,
    const int*   __restrict__ nei,
    float*       __restrict__ out,
    int n_nodes)
{
    const int tid   = blockIdx.x * blockDim.x + threadIdx.x;
    const int group = tid >> 4;
    const int lane  = tid & 15;
    if (group >= n_nodes) return;
    const long base = (long)group * TOPK;
    const float w0 = wei[base + lane];
    const float w1 = wei[base + 16 + lane];
    const int   i0 = nei[base + lane];
    const int   i1 = nei[base + 16 + lane];
    const float m0 = (w0 != 0.0f) ? 1.0f : 0.0f;
    const float m1 = (w1 != 0.0f) ? 1.0f : 0.0f;
    float4 acc = make_float4(0.f, 0.f, 0.f, 0.f);
    float  cnt = 0.0f;
    #pragma unroll 8
    for (int k = 0; k < 16; ++k) {
        const int   j0 = __shfl(i0, k, 16);
        const float a0 = __shfl(m0, k, 16);
        const float4 r0 = *(const float4*)(emb + (size_t)j0 * EMB + lane * 4);
        acc.x += a0*r0.x; acc.y += a0*r0.y; acc.z += a0*r0.z; acc.w += a0*r0.w; cnt += a0;
        const int   j1 = __shfl(i1, k, 16);
        const float a1 = __shfl(m1, k, 16);
        const float4 r1 = *(const float4*)(emb + (size_t)j1 * EMB + lane * 4);
        acc.x += a1*r1.x; acc.y += a1*r1.y; acc.z += a1*r1.z; acc.w += a1*r1.w; cnt += a1;
    }
    const float sc = 1.0f / (cnt + 1e-12f);
    float4 o;
    o.x = acc.x*sc; o.y = acc.y*sc; o.z = acc.z*sc; o.w = acc.w*sc;
    *(float4*)(out + (size_t)group * EMB + lane * 4) = o;
}

extern "C" void kernel_launch(void* const* d_in, const int* in_sizes, int n_in,
                              void* d_out, int out_size, void* d_ws, size_t ws_size,
                              hipStream_t stream) {
    const float* emb = (const float*)d_in[0];   // [N, 64] fp32
    const float* wei = (const float*)d_in[1];   // [N, 32] fp32
    const int*   nei = (const int*)d_in[2];     // [N, 32] int32
    float*       out = (float*)d_out;           // [N, 1, 64] fp32

    const int n_nodes = in_sizes[1] / TOPK;     // 200000

    const size_t emb8_bytes  = (size_t)(n_nodes + 1) * EMB;            // 12.8MB + 64B
    const size_t partial_off = (emb8_bytes + 15) & ~(size_t)15;
    const size_t need_q8     = partial_off + 1024 * sizeof(float) + 16;

    if (ws_size >= need_q8) {
        signed char* emb8   = (signed char*)d_ws;
        float*       partial = (float*)((char*)d_ws + partial_off);
        float*       stepP   = partial + 1024;

        const int total4 = n_nodes * EMB / 4;
        absmax_partial_kernel<<<1024, 256, 0, stream>>>(emb, partial, total4);

        const int a_blocks = (n_nodes * (EMB / 16) + 255) / 256;       // 3125
        quant_kernel<<<a_blocks + 1, 256, 0, stream>>>(
            emb, emb8, partial, stepP, n_nodes, a_blocks);

        const int g_blocks = (n_nodes * 8 + 255) / 256;                // 6250
        gather_q8_kernel<<<g_blocks, 256, 0, stream>>>(
            emb8, wei, nei, stepP, out, n_nodes);
    } else {
        const int threads = n_nodes * 16;
        pprgo_f32_kernel<<<(threads + 255) / 256, 256, 0, stream>>>(
            emb, wei, nei, out, n_nodes);
    }
}